// Round 2
// baseline (190.542 us; speedup 1.0000x reference)
//
#include <hip/hip_runtime.h>

#define NEGF 1.0e12f

constexpr int Hdim = 768;
constexpr int NC   = 160;   // 128 (W1) + 32 (W2) output columns
constexpr int ROWS = 4096;  // B*S
constexpr int SEQ  = 512;
constexpr int KSPLIT = 4;   // K chunks of 192

typedef __attribute__((ext_vector_type(8))) short  short8;   // 8 bf16
typedef __attribute__((ext_vector_type(4))) float  floatx4;

__device__ inline unsigned short f2bf(float f) {
    union { float f; unsigned u; } v; v.f = f;
    return (unsigned short)((v.u + 0x8000u) >> 16);   // round-half-up, fine at this tol
}

// ---------------------------------------------------------------------------
// Kernel A: partial[kc] = x @ [W1|W2] over K-chunk kc, bf16 MFMA 16x16x32.
// (unchanged for attribution)
// ---------------------------------------------------------------------------
__global__ __launch_bounds__(256) void gemm_mfma_k(
    const float* __restrict__ x, const float* __restrict__ W1,
    const float* __restrict__ W2, float* __restrict__ partial)
{
    __shared__ __align__(16) unsigned short xs[64 * 40];
    __shared__ __align__(16) unsigned short ws[NC * 40];

    const int tid  = threadIdx.x;
    const int wave = tid >> 6;
    const int lane = tid & 63;
    const int quad = lane >> 4;
    const int nl   = lane & 15;
    const int r0   = blockIdx.x * 64;
    const int k0   = blockIdx.y * 192;

    floatx4 acc[10];
#pragma unroll
    for (int t = 0; t < 10; t++) acc[t] = (floatx4)(0.0f);

    for (int kt = 0; kt < 192; kt += 32) {
        const int kb = k0 + kt;
        {
            const int row = tid >> 2;
            const int kq  = (tid & 3) * 8;
            const float* xp = x + (size_t)(r0 + row) * Hdim + kb + kq;
            float4 v0 = *(const float4*)xp;
            float4 v1 = *(const float4*)(xp + 4);
            short8 sv;
            sv[0] = (short)f2bf(v0.x); sv[1] = (short)f2bf(v0.y);
            sv[2] = (short)f2bf(v0.z); sv[3] = (short)f2bf(v0.w);
            sv[4] = (short)f2bf(v1.x); sv[5] = (short)f2bf(v1.y);
            sv[6] = (short)f2bf(v1.z); sv[7] = (short)f2bf(v1.w);
            *(short8*)(xs + row * 40 + kq) = sv;
        }
#pragma unroll
        for (int g = 0; g < 3; g++) {
            const int c   = g * 64 + (tid & 63);
            const int kq2 = (tid >> 6) * 8;
            if (c < NC) {
                float f[8];
                if (c < 128) {
                    const float* wp = W1 + (size_t)(kb + kq2) * 128 + c;
#pragma unroll
                    for (int j = 0; j < 8; j++) f[j] = wp[j * 128];
                } else {
                    const float* wp = W2 + (size_t)(kb + kq2) * 32 + (c - 128);
#pragma unroll
                    for (int j = 0; j < 8; j++) f[j] = wp[j * 32];
                }
                short8 sv;
#pragma unroll
                for (int j = 0; j < 8; j++) sv[j] = (short)f2bf(f[j]);
                *(short8*)(ws + c * 40 + kq2) = sv;
            }
        }
        __syncthreads();

        short8 af = *(const short8*)(xs + (wave * 16 + nl) * 40 + quad * 8);
#pragma unroll
        for (int t = 0; t < 10; t++) {
            short8 bf = *(const short8*)(ws + (t * 16 + nl) * 40 + quad * 8);
            acc[t] = __builtin_amdgcn_mfma_f32_16x16x32_bf16(af, bf, acc[t], 0, 0, 0);
        }
        __syncthreads();
    }

    float* pout = partial + (size_t)blockIdx.y * ROWS * NC;
#pragma unroll
    for (int t = 0; t < 10; t++) {
#pragma unroll
        for (int r = 0; r < 4; r++) {
            pout[(size_t)(r0 + wave * 16 + quad * 4 + r) * NC + t * 16 + nl] = acc[t][r];
        }
    }
}

// ---------------------------------------------------------------------------
// Kernel B: combine 4 K-partials + bias, RoPE, emit bf16 start/end
// (unchanged for attribution)
// ---------------------------------------------------------------------------
__global__ __launch_bounds__(256) void combine_rope_k(
    const float* __restrict__ partial, const float* __restrict__ b1,
    const float* __restrict__ b2, unsigned short* __restrict__ startbf,
    unsigned short* __restrict__ endbf, float* __restrict__ tyn,
    float* __restrict__ tym)
{
    const int tid = threadIdx.x;
    const int row = blockIdx.x * 4 + (tid >> 6);
    const int u   = tid & 63;
    const int b   = row >> 9;
    const int s   = row & 511;
    const float* p0 = partial + (size_t)row * NC;
    const size_t cstride = (size_t)ROWS * NC;

    if (u < 32) {
        const int i = u;
        float4 a0 = *(const float4*)(p0 + 4 * i);
        float4 a1 = *(const float4*)(p0 + cstride + 4 * i);
        float4 a2 = *(const float4*)(p0 + 2 * cstride + 4 * i);
        float4 a3 = *(const float4*)(p0 + 3 * cstride + 4 * i);
        float t0 = a0.x + a1.x + a2.x + a3.x + b1[4 * i + 0];
        float t1 = a0.y + a1.y + a2.y + a3.y + b1[4 * i + 1];
        float t2 = a0.z + a1.z + a2.z + a3.z + b1[4 * i + 2];
        float t3 = a0.w + a1.w + a2.w + a3.w + b1[4 * i + 3];
        float freq = __powf(10000.0f, -(float)i * (1.0f / 32.0f));
        float ang  = (float)s * freq;
        float sn, cs;
        __sincosf(ang, &sn, &cs);
        float so0 = (t0 * cs - t2 * sn) * 0.125f;
        float so1 = (t2 * cs + t0 * sn) * 0.125f;
        float eo0 = t1 * cs - t3 * sn;
        float eo1 = t3 * cs + t1 * sn;
        ushort2 sp; sp.x = f2bf(so0); sp.y = f2bf(so1);
        ushort2 ep; ep.x = f2bf(eo0); ep.y = f2bf(eo1);
        *(ushort2*)(startbf + (size_t)row * 64 + 2 * i) = sp;
        *(ushort2*)(endbf   + (size_t)row * 64 + 2 * i) = ep;
    } else {
        const int j = u - 32;
        float t = p0[128 + j] + p0[cstride + 128 + j] + p0[2 * cstride + 128 + j]
                + p0[3 * cstride + 128 + j] + b2[j];
        float v = t * 0.5f;
        const int l = j >> 1;
        if ((j & 1) == 0) tyn[((size_t)b * 16 + l) * SEQ + s] = v;
        else              tym[((size_t)b * 16 + l) * SEQ + s] = v;
    }
}

// ---------------------------------------------------------------------------
// Kernel C v2: transposed-D span tile -> per-lane dwordx4 NT stores.
//  - MFMA operands swapped (A = end rows [n], B = start rows [m]) so the
//    D fragment holds 4 consecutive n per lane -> one dwordx4 NT store per
//    (plane, t) instead of 4 scalar stores.
//  - Grid (8 n, 8 m, 8 b x 2 l-halves) = 1024 blocks (16 waves/CU).
//  - Strictly-lower blocks (m0 > n0) skip staging + MFMA: output there is the
//    exact fp32-absorbed constant derived from masks only (|span+typing| <<
//    ulp(1e12)/2, so x - 1e12 == -1e12 bit-exactly, matching the reference).
// ---------------------------------------------------------------------------
__global__ __launch_bounds__(256) void entity_k(
    const unsigned short* __restrict__ startbf, const unsigned short* __restrict__ endbf,
    const float* __restrict__ tyn, const float* __restrict__ tym,
    const int* __restrict__ amask, float* __restrict__ out)
{
    __shared__ __align__(16) unsigned short sE[64 * 72];  // end rows (n) -> A operand
    __shared__ __align__(16) unsigned short sS[64 * 72];  // start rows (m) -> B operand
    __shared__ float tyn_s[8 * 64];
    __shared__ float tym_s[8 * 64];
    __shared__ float mrow_s[64];
    __shared__ float mcol_s[64];

    const int tid = threadIdx.x;
    const int bz  = blockIdx.z;
    const int b   = bz >> 1;
    const int l0  = (bz & 1) * 8;
    const int m0  = blockIdx.y * 64;
    const int n0  = blockIdx.x * 64;
    const bool lower = (m0 > n0);
    const bool diag  = (m0 == n0);

    if (tid < 64)       mrow_s[tid]      = (float)amask[b * SEQ + m0 + tid];
    else if (tid < 128) mcol_s[tid - 64] = (float)amask[b * SEQ + n0 + (tid - 64)];

    if (!lower) {
        for (int t = tid; t < 512; t += 256) {
            int row = t >> 3;
            int kq  = (t & 7) * 8;
            *(short8*)(sE + row * 72 + kq) =
                *(const short8*)(endbf + (size_t)(b * SEQ + n0 + row) * 64 + kq);
            *(short8*)(sS + row * 72 + kq) =
                *(const short8*)(startbf + (size_t)(b * SEQ + m0 + row) * 64 + kq);
        }
        for (int t = tid; t < 8 * 64; t += 256) {
            int l = t >> 6, i = t & 63;
            tym_s[t] = tym[((size_t)b * 16 + l0 + l) * SEQ + m0 + i];
            tyn_s[t] = tyn[((size_t)b * 16 + l0 + l) * SEQ + n0 + i];
        }
    }
    __syncthreads();

    const int wave  = tid >> 6;
    const int lane  = tid & 63;
    const int quad  = lane >> 4;
    const int nl    = lane & 15;
    const int nloc0 = wave * 16 + quad * 4;   // local n of acc reg r=0

    floatx4 acc[4];
#pragma unroll
    for (int t = 0; t < 4; t++) acc[t] = (floatx4)(0.0f);

    if (!lower) {
        short8 a0 = *(const short8*)(sE + (wave * 16 + nl) * 72 + quad * 8);
        short8 a1 = *(const short8*)(sE + (wave * 16 + nl) * 72 + 32 + quad * 8);
#pragma unroll
        for (int t = 0; t < 4; t++) {
            short8 bf0 = *(const short8*)(sS + (t * 16 + nl) * 72 + quad * 8);
            short8 bf1 = *(const short8*)(sS + (t * 16 + nl) * 72 + 32 + quad * 8);
            acc[t] = __builtin_amdgcn_mfma_f32_16x16x32_bf16(a0, bf0, acc[t], 0, 0, 0);
            acc[t] = __builtin_amdgcn_mfma_f32_16x16x32_bf16(a1, bf1, acc[t], 0, 0, 0);
        }
    }

    // masks: col (n) varies with reg r, row (m) varies with t
    float mc4[4], cadd4[4];
#pragma unroll
    for (int r = 0; r < 4; r++) {
        mc4[r]   = mcol_s[nloc0 + r];
        cadd4[r] = -NEGF * (1.0f - mc4[r]);
    }
    float mrt[4], raddt[4];
#pragma unroll
    for (int t = 0; t < 4; t++) {
        mrt[t]   = mrow_s[t * 16 + nl];
        raddt[t] = -NEGF * (1.0f - mrt[t]);
    }

    for (int l = 0; l < 8; l++) {
        floatx4 tn4 = (floatx4)(0.0f);
        if (!lower) tn4 = *(const floatx4*)(tyn_s + l * 64 + nloc0);
        float* op = out + (((size_t)(b * 16 + l0 + l)) * SEQ + m0) * SEQ + n0 + nloc0;
#pragma unroll
        for (int t = 0; t < 4; t++) {
            float tm = lower ? 0.0f : tym_s[l * 64 + t * 16 + nl];
            floatx4 v;
#pragma unroll
            for (int r = 0; r < 4; r++) {
                float x = acc[t][r] + tn4[r] + tm;
                x = x * mrt[t] + raddt[t];
                x = x * mc4[r] + cadd4[r];
                if (lower) x -= NEGF;
                else if (diag && (t * 16 + nl) > (nloc0 + r)) x -= NEGF;
                v[r] = x;
            }
            __builtin_nontemporal_store(v, (floatx4*)(op + (size_t)(t * 16 + nl) * SEQ));
        }
    }
}

// ---------------------------------------------------------------------------
extern "C" void kernel_launch(void* const* d_in, const int* in_sizes, int n_in,
                              void* d_out, int out_size, void* d_ws, size_t ws_size,
                              hipStream_t stream) {
    const float* x     = (const float*)d_in[0];
    const float* W1    = (const float*)d_in[1];
    const float* b1    = (const float*)d_in[2];
    const float* W2    = (const float*)d_in[3];
    const float* b2    = (const float*)d_in[4];
    const int*   amask = (const int*)d_in[5];
    float* out = (float*)d_out;

    char* base = (char*)d_ws;
    float*          partial = (float*)base;                                 // 4*4096*160*4 B
    unsigned short* startbf = (unsigned short*)(base + 10485760);           // 4096*64*2 B
    unsigned short* endbf   = (unsigned short*)(base + 10485760 + 524288);
    float*          tyn     = (float*)(base + 10485760 + 2 * 524288);       // 8*16*512*4 B
    float*          tym     = (float*)(base + 10485760 + 2 * 524288 + 262144);

    hipLaunchKernelGGL(gemm_mfma_k, dim3(64, KSPLIT), dim3(256), 0, stream,
                       x, W1, W2, partial);
    hipLaunchKernelGGL(combine_rope_k, dim3(ROWS / 4), dim3(256), 0, stream,
                       partial, b1, b2, startbf, endbf, tyn, tym);
    hipLaunchKernelGGL(entity_k, dim3(8, 8, 16), dim3(256), 0, stream,
                       startbf, endbf, tyn, tym, amask, out);
}

// Round 3
// 175.259 us; speedup vs baseline: 1.0872x; 1.0872x over previous
//
#include <hip/hip_runtime.h>

#define NEGF 1.0e12f

constexpr int Hdim = 768;
constexpr int NC   = 160;   // 128 (W1) + 32 (W2) output columns
constexpr int ROWS = 4096;  // B*S
constexpr int SEQ  = 512;
constexpr int KSPLIT = 4;   // K chunks of 192

typedef __attribute__((ext_vector_type(8))) short  short8;   // 8 bf16
typedef __attribute__((ext_vector_type(4))) float  floatx4;

__device__ inline unsigned short f2bf(float f) {
    union { float f; unsigned u; } v; v.f = f;
    return (unsigned short)((v.u + 0x8000u) >> 16);   // round-half-up, fine at this tol
}

// ---------------------------------------------------------------------------
// Kernel A: partial[kc] = x @ [W1|W2] over K-chunk kc, bf16 MFMA 16x16x32.
// (unchanged for attribution)
// ---------------------------------------------------------------------------
__global__ __launch_bounds__(256) void gemm_mfma_k(
    const float* __restrict__ x, const float* __restrict__ W1,
    const float* __restrict__ W2, float* __restrict__ partial)
{
    __shared__ __align__(16) unsigned short xs[64 * 40];
    __shared__ __align__(16) unsigned short ws[NC * 40];

    const int tid  = threadIdx.x;
    const int wave = tid >> 6;
    const int lane = tid & 63;
    const int quad = lane >> 4;
    const int nl   = lane & 15;
    const int r0   = blockIdx.x * 64;
    const int k0   = blockIdx.y * 192;

    floatx4 acc[10];
#pragma unroll
    for (int t = 0; t < 10; t++) acc[t] = (floatx4)(0.0f);

    for (int kt = 0; kt < 192; kt += 32) {
        const int kb = k0 + kt;
        {
            const int row = tid >> 2;
            const int kq  = (tid & 3) * 8;
            const float* xp = x + (size_t)(r0 + row) * Hdim + kb + kq;
            float4 v0 = *(const float4*)xp;
            float4 v1 = *(const float4*)(xp + 4);
            short8 sv;
            sv[0] = (short)f2bf(v0.x); sv[1] = (short)f2bf(v0.y);
            sv[2] = (short)f2bf(v0.z); sv[3] = (short)f2bf(v0.w);
            sv[4] = (short)f2bf(v1.x); sv[5] = (short)f2bf(v1.y);
            sv[6] = (short)f2bf(v1.z); sv[7] = (short)f2bf(v1.w);
            *(short8*)(xs + row * 40 + kq) = sv;
        }
#pragma unroll
        for (int g = 0; g < 3; g++) {
            const int c   = g * 64 + (tid & 63);
            const int kq2 = (tid >> 6) * 8;
            if (c < NC) {
                float f[8];
                if (c < 128) {
                    const float* wp = W1 + (size_t)(kb + kq2) * 128 + c;
#pragma unroll
                    for (int j = 0; j < 8; j++) f[j] = wp[j * 128];
                } else {
                    const float* wp = W2 + (size_t)(kb + kq2) * 32 + (c - 128);
#pragma unroll
                    for (int j = 0; j < 8; j++) f[j] = wp[j * 32];
                }
                short8 sv;
#pragma unroll
                for (int j = 0; j < 8; j++) sv[j] = (short)f2bf(f[j]);
                *(short8*)(ws + c * 40 + kq2) = sv;
            }
        }
        __syncthreads();

        short8 af = *(const short8*)(xs + (wave * 16 + nl) * 40 + quad * 8);
#pragma unroll
        for (int t = 0; t < 10; t++) {
            short8 bf = *(const short8*)(ws + (t * 16 + nl) * 40 + quad * 8);
            acc[t] = __builtin_amdgcn_mfma_f32_16x16x32_bf16(af, bf, acc[t], 0, 0, 0);
        }
        __syncthreads();
    }

    float* pout = partial + (size_t)blockIdx.y * ROWS * NC;
#pragma unroll
    for (int t = 0; t < 10; t++) {
#pragma unroll
        for (int r = 0; r < 4; r++) {
            pout[(size_t)(r0 + wave * 16 + quad * 4 + r) * NC + t * 16 + nl] = acc[t][r];
        }
    }
}

// ---------------------------------------------------------------------------
// Kernel B: combine 4 K-partials + bias, RoPE, emit bf16 start/end
// (unchanged for attribution)
// ---------------------------------------------------------------------------
__global__ __launch_bounds__(256) void combine_rope_k(
    const float* __restrict__ partial, const float* __restrict__ b1,
    const float* __restrict__ b2, unsigned short* __restrict__ startbf,
    unsigned short* __restrict__ endbf, float* __restrict__ tyn,
    float* __restrict__ tym)
{
    const int tid = threadIdx.x;
    const int row = blockIdx.x * 4 + (tid >> 6);
    const int u   = tid & 63;
    const int b   = row >> 9;
    const int s   = row & 511;
    const float* p0 = partial + (size_t)row * NC;
    const size_t cstride = (size_t)ROWS * NC;

    if (u < 32) {
        const int i = u;
        float4 a0 = *(const float4*)(p0 + 4 * i);
        float4 a1 = *(const float4*)(p0 + cstride + 4 * i);
        float4 a2 = *(const float4*)(p0 + 2 * cstride + 4 * i);
        float4 a3 = *(const float4*)(p0 + 3 * cstride + 4 * i);
        float t0 = a0.x + a1.x + a2.x + a3.x + b1[4 * i + 0];
        float t1 = a0.y + a1.y + a2.y + a3.y + b1[4 * i + 1];
        float t2 = a0.z + a1.z + a2.z + a3.z + b1[4 * i + 2];
        float t3 = a0.w + a1.w + a2.w + a3.w + b1[4 * i + 3];
        float freq = __powf(10000.0f, -(float)i * (1.0f / 32.0f));
        float ang  = (float)s * freq;
        float sn, cs;
        __sincosf(ang, &sn, &cs);
        float so0 = (t0 * cs - t2 * sn) * 0.125f;
        float so1 = (t2 * cs + t0 * sn) * 0.125f;
        float eo0 = t1 * cs - t3 * sn;
        float eo1 = t3 * cs + t1 * sn;
        ushort2 sp; sp.x = f2bf(so0); sp.y = f2bf(so1);
        ushort2 ep; ep.x = f2bf(eo0); ep.y = f2bf(eo1);
        *(ushort2*)(startbf + (size_t)row * 64 + 2 * i) = sp;
        *(ushort2*)(endbf   + (size_t)row * 64 + 2 * i) = ep;
    } else {
        const int j = u - 32;
        float t = p0[128 + j] + p0[cstride + 128 + j] + p0[2 * cstride + 128 + j]
                + p0[3 * cstride + 128 + j] + b2[j];
        float v = t * 0.5f;
        const int l = j >> 1;
        if ((j & 1) == 0) tyn[((size_t)b * 16 + l) * SEQ + s] = v;
        else              tym[((size_t)b * 16 + l) * SEQ + s] = v;
    }
}

// ---------------------------------------------------------------------------
// Kernel C1: span[b][m][n] = start[m] . end[n]  (bf16 MFMA, upper tiles only).
// 8 MB f32, overlaid on the dead `partial` buffer. Lower tiles skipped (their
// span values are never consumed: bcast_k zeroes span for n<m before use).
// ---------------------------------------------------------------------------
__global__ __launch_bounds__(256) void span_k(
    const unsigned short* __restrict__ startbf, const unsigned short* __restrict__ endbf,
    float* __restrict__ span)
{
    const int b  = blockIdx.z;
    const int m0 = blockIdx.y * 64;
    const int n0 = blockIdx.x * 64;
    if (m0 > n0) return;   // strictly-lower 64x64 tile: never consumed

    __shared__ __align__(16) unsigned short sA[64 * 72];  // start rows (m)
    __shared__ __align__(16) unsigned short sB[64 * 72];  // end rows (n)

    const int tid = threadIdx.x;
    for (int t = tid; t < 512; t += 256) {
        int row = t >> 3;
        int kq  = (t & 7) * 8;
        *(short8*)(sA + row * 72 + kq) =
            *(const short8*)(startbf + (size_t)(b * SEQ + m0 + row) * 64 + kq);
        *(short8*)(sB + row * 72 + kq) =
            *(const short8*)(endbf + (size_t)(b * SEQ + n0 + row) * 64 + kq);
    }
    __syncthreads();

    const int wave = tid >> 6;
    const int lane = tid & 63;
    const int quad = lane >> 4;
    const int nl   = lane & 15;

    short8 a0 = *(const short8*)(sA + (wave * 16 + nl) * 72 + quad * 8);
    short8 a1 = *(const short8*)(sA + (wave * 16 + nl) * 72 + 32 + quad * 8);

    floatx4 acc[4];
#pragma unroll
    for (int t = 0; t < 4; t++) acc[t] = (floatx4)(0.0f);
#pragma unroll
    for (int t = 0; t < 4; t++) {
        short8 bf0 = *(const short8*)(sB + (t * 16 + nl) * 72 + quad * 8);
        short8 bf1 = *(const short8*)(sB + (t * 16 + nl) * 72 + 32 + quad * 8);
        acc[t] = __builtin_amdgcn_mfma_f32_16x16x32_bf16(a0, bf0, acc[t], 0, 0, 0);
        acc[t] = __builtin_amdgcn_mfma_f32_16x16x32_bf16(a1, bf1, acc[t], 0, 0, 0);
    }

    // D layout: row (m-local) = wave*16 + quad*4 + r, col (n-local) = t*16 + nl
#pragma unroll
    for (int t = 0; t < 4; t++) {
#pragma unroll
        for (int r = 0; r < 4; r++) {
            span[((size_t)(b * SEQ) + m0 + wave * 16 + quad * 4 + r) * SEQ
                 + n0 + t * 16 + nl] = acc[t][r];
        }
    }
}

// ---------------------------------------------------------------------------
// Kernel C2: pure broadcast-writer. Block = 8 m-rows x 512 n x 8 l-planes.
// Lane layout: row r = tid>>5, cols (tid&31)*4 + q*128 -> every float4 store
// is 2 segments x 512 B contiguous (32 lanes x 16 B per row). All l-invariant
// terms (span, mask FMA constants, tril fold) hoisted to registers; LDS holds
// only tyn (16 KB, conflict-free b128: lanes 16 B-strided).
// Exactness: mask chain + tril fold are fp32-exact (constants are multiples
// of 2^16; |span+typing| << ulp(1e12)/2), matching the reference ops in order.
// ---------------------------------------------------------------------------
__global__ __launch_bounds__(256) void bcast_k(
    const float* __restrict__ span, const float* __restrict__ tyn,
    const float* __restrict__ tym, const int* __restrict__ amask,
    float* __restrict__ out)
{
    __shared__ float tyn_s[8 * SEQ];
    __shared__ float tym_s[64];

    const int tid = threadIdx.x;
    const int m0  = blockIdx.x * 8;
    const int l0  = blockIdx.y * 8;
    const int b   = blockIdx.z;

    for (int t = tid; t < 8 * SEQ / 4; t += 256)
        ((floatx4*)tyn_s)[t] = ((const floatx4*)(tyn + ((size_t)b * 16 + l0) * SEQ))[t];
    if (tid < 64) {
        int l = tid >> 3, r = tid & 7;
        tym_s[tid] = tym[((size_t)b * 16 + l0 + l) * SEQ + m0 + r];
    }

    const int r  = tid >> 5;
    const int cb = (tid & 31) * 4;
    const int m  = m0 + r;
    const float mr   = (float)amask[b * SEQ + m];
    const float radd = -NEGF * (1.0f - mr);

    float spanz[16], mc[16], cadd2[16];
#pragma unroll
    for (int q = 0; q < 4; q++) {
        floatx4 s4 = *(const floatx4*)(span + ((size_t)b * SEQ + m) * SEQ + cb + q * 128);
        int4 mk = *(const int4*)(amask + b * SEQ + cb + q * 128);
        const int* mki = (const int*)&mk;
#pragma unroll
        for (int e = 0; e < 4; e++) {
            const int j = q * 4 + e;
            const int n = cb + q * 128 + e;
            mc[j] = (float)mki[e];
            float ca = -NEGF * (1.0f - mc[j]);
            cadd2[j] = (n < m) ? (ca - NEGF) : ca;   // fold tril subtraction (exact)
            spanz[j] = (n >= m) ? s4[e] : 0.0f;      // lower span never consumed
        }
    }
    __syncthreads();

    for (int l = 0; l < 8; l++) {
        const float tm = tym_s[l * 8 + r];
        float* orow = out + (((size_t)(b * 16 + l0 + l)) * SEQ + m) * SEQ;
#pragma unroll
        for (int q = 0; q < 4; q++) {
            floatx4 t4 = *(const floatx4*)(tyn_s + l * SEQ + cb + q * 128);
            floatx4 v;
#pragma unroll
            for (int e = 0; e < 4; e++) {
                const int j = q * 4 + e;
                float x = spanz[j] + t4[e] + tm;
                x = x * mr + radd;
                x = x * mc[j] + cadd2[j];
                v[e] = x;
            }
            *(floatx4*)(orow + cb + q * 128) = v;
        }
    }
}

// ---------------------------------------------------------------------------
extern "C" void kernel_launch(void* const* d_in, const int* in_sizes, int n_in,
                              void* d_out, int out_size, void* d_ws, size_t ws_size,
                              hipStream_t stream) {
    const float* x     = (const float*)d_in[0];
    const float* W1    = (const float*)d_in[1];
    const float* b1    = (const float*)d_in[2];
    const float* W2    = (const float*)d_in[3];
    const float* b2    = (const float*)d_in[4];
    const int*   amask = (const int*)d_in[5];
    float* out = (float*)d_out;

    char* base = (char*)d_ws;
    float*          partial = (float*)base;                                 // 4*4096*160*4 B
    unsigned short* startbf = (unsigned short*)(base + 10485760);           // 4096*64*2 B
    unsigned short* endbf   = (unsigned short*)(base + 10485760 + 524288);
    float*          tyn     = (float*)(base + 10485760 + 2 * 524288);       // 8*16*512*4 B
    float*          tym     = (float*)(base + 10485760 + 2 * 524288 + 262144);
    float*          span    = partial;  // overlay: partial is dead after combine_rope_k
                                        // span = 8*512*512*4 B = 8.4 MB < 10.5 MB

    hipLaunchKernelGGL(gemm_mfma_k, dim3(64, KSPLIT), dim3(256), 0, stream,
                       x, W1, W2, partial);
    hipLaunchKernelGGL(combine_rope_k, dim3(ROWS / 4), dim3(256), 0, stream,
                       partial, b1, b2, startbf, endbf, tyn, tym);
    hipLaunchKernelGGL(span_k, dim3(8, 8, 8), dim3(256), 0, stream,
                       startbf, endbf, span);
    hipLaunchKernelGGL(bcast_k, dim3(64, 2, 8), dim3(256), 0, stream,
                       span, tyn, tym, amask, out);
}